// Round 2
// baseline (597.534 us; speedup 1.0000x reference)
//
#include <hip/hip_runtime.h>
#include <hip/hip_bf16.h>

// MHN update kernel: out = v + 0.5*mask*(softmax_m(mem@v^T - 0.5*||mem||^2)^T @ mem - v)
// Split-M flash attention: 256 WGs each own 256 memories (2 chunks of 128),
// online softmax, bf16 partials, then a combine kernel.

#define D_DIM 256
#define B_DIM 512
#define M_TOT 65536
#define NSPLIT 256   // stage-1 workgroups; 256 memories per WG
#define CHUNK 128    // memories staged in LDS at a time

typedef __attribute__((ext_vector_type(4))) float f32x4;
typedef __attribute__((ext_vector_type(8))) short s16x8;
typedef __attribute__((ext_vector_type(2))) unsigned int u32x2;
typedef __attribute__((ext_vector_type(4))) unsigned int u32x4;

__device__ __forceinline__ unsigned short bf16rn(float f) {
  unsigned x = __builtin_bit_cast(unsigned, f);
  x += 0x7fffu + ((x >> 16) & 1u);
  return (unsigned short)(x >> 16);
}
__device__ __forceinline__ unsigned pk2(float a, float b) {
  return (unsigned)bf16rn(a) | ((unsigned)bf16rn(b) << 16);
}
__device__ __forceinline__ float bf2f(unsigned short u) {
  return __builtin_bit_cast(float, ((unsigned)u) << 16);
}

// ---------------- kernel 0: v f32 -> bf16 ----------------
__global__ __launch_bounds__(256) void k_vcvt(const float* __restrict__ v,
                                              unsigned short* __restrict__ vbf) {
  int t = blockIdx.x * 256 + threadIdx.x;   // 32768 threads, 4 elems each
  f32x4 f = *reinterpret_cast<const f32x4*>(v + (size_t)t * 4);
  u32x2 p;
  p[0] = pk2(f[0], f[1]);
  p[1] = pk2(f[2], f[3]);
  *reinterpret_cast<u32x2*>(vbf + (size_t)t * 4) = p;
}

// ---------------- kernel 1: split-M flash ----------------
// Per WG: m in [wg*256, wg*256+256), all 512 b.
// Wave w handles b-tile of 32 (two 16-col fragments cf=0,1) per b-iteration.
// Swapped QK^T: S[m][b] = mfma(A=mem[m][d], B=v^T[d][b]) -> C lane (g,c):
//   S[m = rf*16 + 4g + r][b = bw + cf*16 + c]
// PV: O[b][d] = mfma(A=P^T (via lane-group shuffle), B=memT); C-layout rows
// are b = 4g+r (NOT c!) so the online rescale must be broadcast to rows.
__global__ __launch_bounds__(512, 2) void k_stage1(
    const float* __restrict__ memg, const unsigned short* __restrict__ vbf,
    unsigned short* __restrict__ part_o, float* __restrict__ part_m,
    float* __restrict__ part_l) {
  __shared__ __align__(16) char Ab[CHUNK * D_DIM * 2];  // [m][d] bf16, swz ^((m&7)<<4)
  __shared__ __align__(16) char Tb[D_DIM * CHUNK * 2];  // [d][m] bf16, swz ^((d&7)<<4)
  __shared__ __align__(16) float msq[CHUNK];

  const int tid = (int)threadIdx.x;
  const int w = tid >> 6;
  const int lane = tid & 63;
  const int g = lane >> 4;
  const int c = lane & 15;
  const int wg = (int)blockIdx.x;

  for (int biter = 0; biter < 2; ++biter) {
    const int bw = biter * 256 + w * 32;
    f32x4 acc[2][16];
#pragma unroll
    for (int cf = 0; cf < 2; ++cf)
#pragma unroll
      for (int n = 0; n < 16; ++n) acc[cf][n] = (f32x4)0.0f;
    float rm0 = -__builtin_inff(), rm1 = -__builtin_inff();
    float rs0 = 0.f, rs1 = 0.f;

    for (int ch = 0; ch < 2; ++ch) {
      const size_t mc = (size_t)wg * 256 + (size_t)ch * CHUNK;
      __syncthreads();  // previous chunk's readers done
      // ---- pass A: global f32 -> Ab (bf16, swizzled) + msq (f32 row sumsq)
#pragma unroll
      for (int it = 0; it < 16; ++it) {
        int m = it * 8 + w;
        f32x4 f = *reinterpret_cast<const f32x4*>(memg + (mc + (size_t)m) * D_DIM + lane * 4);
        u32x2 pw;
        pw[0] = pk2(f[0], f[1]);
        pw[1] = pk2(f[2], f[3]);
        int byteA = (m * 512 + lane * 8) ^ ((m & 7) << 4);
        *reinterpret_cast<u32x2*>(Ab + byteA) = pw;
        float sq = f[0] * f[0] + f[1] * f[1] + f[2] * f[2] + f[3] * f[3];
#pragma unroll
        for (int s = 32; s; s >>= 1) sq += __shfl_xor(sq, s);
        if (lane == 0) msq[m] = sq;
      }
      __syncthreads();
      // ---- pass B: transpose Ab -> Tb
      {
        int d = tid & 255;
        int mhalf = (tid >> 8) * 4;
#pragma unroll
        for (int j = 0; j < 16; ++j) {
          int m0 = j * 8 + mhalf;
          unsigned short e0 = *reinterpret_cast<unsigned short*>(
              Ab + (((m0 + 0) * 512 + d * 2) ^ (((m0 + 0) & 7) << 4)));
          unsigned short e1 = *reinterpret_cast<unsigned short*>(
              Ab + (((m0 + 1) * 512 + d * 2) ^ (((m0 + 1) & 7) << 4)));
          unsigned short e2 = *reinterpret_cast<unsigned short*>(
              Ab + (((m0 + 2) * 512 + d * 2) ^ (((m0 + 2) & 7) << 4)));
          unsigned short e3 = *reinterpret_cast<unsigned short*>(
              Ab + (((m0 + 3) * 512 + d * 2) ^ (((m0 + 3) & 7) << 4)));
          u32x2 pw;
          pw[0] = (unsigned)e0 | ((unsigned)e1 << 16);
          pw[1] = (unsigned)e2 | ((unsigned)e3 << 16);
          int byteT = (d * 256 + m0 * 2) ^ ((d & 7) << 4);
          *reinterpret_cast<u32x2*>(Tb + byteT) = pw;
        }
      }
      __syncthreads();

      // ---- QK^T (swapped): S[2 cf][8 rf]
      f32x4 S[2][8];
#pragma unroll
      for (int cf = 0; cf < 2; ++cf)
#pragma unroll
        for (int rf = 0; rf < 8; ++rf) S[cf][rf] = (f32x4)0.0f;
#pragma unroll
      for (int k = 0; k < 8; ++k) {
        s16x8 bv0 = *reinterpret_cast<const s16x8*>(vbf + (size_t)(bw + c) * D_DIM + k * 32 + g * 8);
        s16x8 bv1 = *reinterpret_cast<const s16x8*>(vbf + (size_t)(bw + 16 + c) * D_DIM + k * 32 + g * 8);
#pragma unroll
        for (int rf = 0; rf < 8; ++rf) {
          int byteA = ((rf * 16 + c) * 512 + (k * 32 + g * 8) * 2) ^ ((c & 7) << 4);
          s16x8 a = *reinterpret_cast<const s16x8*>(Ab + byteA);
          S[0][rf] = __builtin_amdgcn_mfma_f32_16x16x32_bf16(a, bv0, S[0][rf], 0, 0, 0);
          S[1][rf] = __builtin_amdgcn_mfma_f32_16x16x32_bf16(a, bv1, S[1][rf], 0, 0, 0);
        }
      }
      // bias: S -= 0.5*||mem_m||^2   (row m = rf*16 + 4g + r)
#pragma unroll
      for (int rf = 0; rf < 8; ++rf) {
        f32x4 q = *reinterpret_cast<const f32x4*>(msq + rf * 16 + g * 4);
#pragma unroll
        for (int r = 0; r < 4; ++r) {
          S[0][rf][r] -= 0.5f * q[r];
          S[1][rf][r] -= 0.5f * q[r];
        }
      }
      // ---- online softmax per cf (column b = bw + cf*16 + c)
#pragma unroll
      for (int cf = 0; cf < 2; ++cf) {
        float rm = cf ? rm1 : rm0;
        float rs = cf ? rs1 : rs0;
        float mx = -__builtin_inff();
#pragma unroll
        for (int rf = 0; rf < 8; ++rf)
#pragma unroll
          for (int r = 0; r < 4; ++r) mx = fmaxf(mx, S[cf][rf][r]);
        mx = fmaxf(mx, __shfl_xor(mx, 16));
        mx = fmaxf(mx, __shfl_xor(mx, 32));
        float nm = fmaxf(rm, mx);
        float al = __expf(rm - nm);
        float ls = 0.f;
#pragma unroll
        for (int rf = 0; rf < 8; ++rf)
#pragma unroll
          for (int r = 0; r < 4; ++r) {
            float p = __expf(S[cf][rf][r] - nm);
            S[cf][rf][r] = p;
            ls += p;
          }
        ls += __shfl_xor(ls, 16);
        ls += __shfl_xor(ls, 32);
        rs = rs * al + ls;
        // FIX: acc rows are b = 4g+r, but al is the stat of column b = c.
        // Broadcast al to the accumulator's row basis (al is g-uniform, so
        // lane 4g+r of group 0 carries the right value).
        f32x4 alv;
#pragma unroll
        for (int r = 0; r < 4; ++r) alv[r] = __shfl(al, 4 * g + r);
#pragma unroll
        for (int n = 0; n < 16; ++n) acc[cf][n] *= alv;
        if (cf) { rm1 = nm; rs1 = rs; } else { rm0 = nm; rs0 = rs; }
      }
      // ---- PV: acc[cf][n] += P^T @ memT
#pragma unroll
      for (int kk = 0; kk < 4; ++kk) {
        s16x8 pa[2];
#pragma unroll
        for (int cf = 0; cf < 2; ++cf) {
          unsigned q00 = pk2(S[cf][2 * kk][0], S[cf][2 * kk][1]);
          unsigned q01 = pk2(S[cf][2 * kk][2], S[cf][2 * kk][3]);
          unsigned q10 = pk2(S[cf][2 * kk + 1][0], S[cf][2 * kk + 1][1]);
          unsigned q11 = pk2(S[cf][2 * kk + 1][2], S[cf][2 * kk + 1][3]);
          int srcA = ((lane & 16) >> 3) * 16 + c;  // lane-group 2*(g&1), same c
          int srcB = srcA + 16;
          unsigned a0 = (unsigned)__shfl((int)q00, srcA);
          unsigned b0 = (unsigned)__shfl((int)q10, srcA);
          unsigned a1 = (unsigned)__shfl((int)q01, srcA);
          unsigned b1 = (unsigned)__shfl((int)q11, srcA);
          unsigned a2 = (unsigned)__shfl((int)q00, srcB);
          unsigned b2 = (unsigned)__shfl((int)q10, srcB);
          unsigned a3 = (unsigned)__shfl((int)q01, srcB);
          unsigned b3 = (unsigned)__shfl((int)q11, srcB);
          bool hi = lane >= 32;  // g>>1 selects which source fragment
          u32x4 wv;
          wv[0] = hi ? b0 : a0;
          wv[1] = hi ? b1 : a1;
          wv[2] = hi ? b2 : a2;
          wv[3] = hi ? b3 : a3;
          pa[cf] = __builtin_bit_cast(s16x8, wv);
        }
#pragma unroll
        for (int n = 0; n < 16; ++n) {
          int byteT = ((n * 16 + c) * 256 + (kk * 32 + g * 8) * 2) ^ ((c & 7) << 4);
          s16x8 bm = *reinterpret_cast<const s16x8*>(Tb + byteT);
          acc[0][n] = __builtin_amdgcn_mfma_f32_16x16x32_bf16(pa[0], bm, acc[0][n], 0, 0, 0);
          acc[1][n] = __builtin_amdgcn_mfma_f32_16x16x32_bf16(pa[1], bm, acc[1][n], 0, 0, 0);
        }
      }
    }  // ch

    // ---- store partials: part_o[wg][d][b] bf16, stats [wg][b] f32
#pragma unroll
    for (int cf = 0; cf < 2; ++cf) {
      if (g == 0) {
        int b = bw + cf * 16 + c;
        part_m[(size_t)wg * B_DIM + b] = cf ? rm1 : rm0;
        part_l[(size_t)wg * B_DIM + b] = cf ? rs1 : rs0;
      }
#pragma unroll
      for (int n = 0; n < 16; ++n) {
        int d = n * 16 + c;
        int b = bw + cf * 16 + g * 4;  // 4 consecutive b in regs
        u32x2 pw;
        pw[0] = pk2(acc[cf][n][0], acc[cf][n][1]);
        pw[1] = pk2(acc[cf][n][2], acc[cf][n][3]);
        *reinterpret_cast<u32x2*>(part_o + ((size_t)(wg * D_DIM + d)) * B_DIM + b) = pw;
      }
    }
  }  // biter
}

// ---------------- kernel 2: per-b combine scale[g][b] ----------------
__global__ __launch_bounds__(256) void k_scale(const float* __restrict__ part_m,
                                               const float* __restrict__ part_l,
                                               float* __restrict__ scale) {
  int b = blockIdx.x;
  int t = threadIdx.x;  // t = g (NSPLIT==256)
  float m = part_m[(size_t)t * B_DIM + b];
  float l = part_l[(size_t)t * B_DIM + b];
  __shared__ float sm[256];
  sm[t] = m;
  __syncthreads();
  for (int s = 128; s; s >>= 1) {
    if (t < s) sm[t] = fmaxf(sm[t], sm[t + s]);
    __syncthreads();
  }
  float M = sm[0];
  __syncthreads();
  float e = __expf(m - M);
  sm[t] = l * e;
  __syncthreads();
  for (int s = 128; s; s >>= 1) {
    if (t < s) sm[t] += sm[t + s];
    __syncthreads();
  }
  float Z = sm[0];
  scale[(size_t)t * B_DIM + b] = e / Z;
}

// ---------------- kernel 3: reduce partials + epilogue ----------------
__global__ __launch_bounds__(512) void k_out(const unsigned short* __restrict__ part_o,
                                             const float* __restrict__ scale,
                                             const float* __restrict__ v,
                                             const float* __restrict__ mask,
                                             float* __restrict__ out) {
  int d = blockIdx.x;
  int b = threadIdx.x;
  float a = 0.f;
#pragma unroll 4
  for (int gi = 0; gi < NSPLIT; ++gi) {
    float sc = scale[(size_t)gi * B_DIM + b];
    unsigned short u = part_o[((size_t)(gi * D_DIM + d)) * B_DIM + b];
    a = fmaf(sc, bf2f(u), a);
  }
  size_t idx = (size_t)b * D_DIM + d;
  float vv = v[idx];
  float mm = mask[idx];
  out[idx] = vv + 0.5f * (a - vv) * mm;
}

extern "C" void kernel_launch(void* const* d_in, const int* in_sizes, int n_in,
                              void* d_out, int out_size, void* d_ws, size_t ws_size,
                              hipStream_t stream) {
  const float* v = (const float*)d_in[0];       // [512,256]
  const float* mask = (const float*)d_in[1];    // [512,256]
  const float* memg = (const float*)d_in[2];    // [65536,256]
  float* out = (float*)d_out;                   // [512,256] f32

  char* ws = (char*)d_ws;
  const size_t SZ_PO = (size_t)NSPLIT * D_DIM * B_DIM * 2;  // 64 MiB
  const size_t SZ_ST = (size_t)NSPLIT * B_DIM * 4;          // 512 KiB each
  unsigned short* part_o = (unsigned short*)ws;
  float* part_m = (float*)(ws + SZ_PO);
  float* part_l = (float*)(ws + SZ_PO + SZ_ST);
  float* scale = (float*)(ws + SZ_PO + 2 * SZ_ST);
  unsigned short* vbf = (unsigned short*)(ws + SZ_PO + 3 * SZ_ST);

  k_vcvt<<<dim3(128), dim3(256), 0, stream>>>(v, vbf);
  k_stage1<<<dim3(NSPLIT), dim3(512), 0, stream>>>(memg, vbf, part_o, part_m, part_l);
  k_scale<<<dim3(B_DIM), dim3(256), 0, stream>>>(part_m, part_l, scale);
  k_out<<<dim3(D_DIM), dim3(512), 0, stream>>>(part_o, scale, v, mask, out);
}

// Round 3
// 98.742 us; speedup vs baseline: 6.0515x; 6.0515x over previous
//
#include <hip/hip_runtime.h>
#include <hip/hip_bf16.h>

// out = v + 0.5*mask*(softmax_m(mem@v^T - 0.5*||mem||^2)^T @ mem - v)
// Split-M flash attention, restructured for latency hiding:
//  k_prep  : memories f32 -> bf16 (memA) + row sumsq (msq); v -> bf16 (vbf)
//  k_stage1: 256 WGs = 64 m-splits x 4 b-tiles. 16 chunks of 64 m, double-
//            buffered global_load_lds staging (async across raw barriers),
//            vectorized in-LDS transpose, per-wave 16-b online softmax,
//            LDS-staged epilogue writing contiguous part_o[s][b][d] rows.
//  k_scale : combine per-split softmax stats -> scale[b][s]
//  k_out   : sum partials + epilogue

#define D_DIM 256
#define B_DIM 512
#define M_TOT 65536
#define NSPLIT 64      // m-splits; 1024 m per split
#define CHUNK 64       // m per LDS chunk; 16 chunks per split
#define NCHUNK 16

typedef __attribute__((ext_vector_type(4))) float f32x4;
typedef __attribute__((ext_vector_type(8))) short s16x8;
typedef __attribute__((ext_vector_type(2))) unsigned int u32x2;
typedef __attribute__((ext_vector_type(4))) unsigned int u32x4;

__device__ __forceinline__ unsigned short bf16rn(float f) {
  unsigned x = __builtin_bit_cast(unsigned, f);
  x += 0x7fffu + ((x >> 16) & 1u);
  return (unsigned short)(x >> 16);
}
__device__ __forceinline__ unsigned pk2(float a, float b) {
  return (unsigned)bf16rn(a) | ((unsigned)bf16rn(b) << 16);
}
__device__ __forceinline__ float bf2f(unsigned short u) {
  return __builtin_bit_cast(float, ((unsigned)u) << 16);
}

// Tb swizzle: spreads both transpose-writes (d varies per lane) and PV reads
// (c&7 varies) across the 8 16B slots of a 128B row.
#define TSWZ(d) ((((d) ^ ((d) >> 3)) & 7) << 4)

// ---------------- kernel 0: prep ----------------
__global__ __launch_bounds__(512) void k_prep(const float* __restrict__ memg,
                                              const float* __restrict__ v,
                                              unsigned short* __restrict__ memA,
                                              unsigned short* __restrict__ vbf,
                                              float* __restrict__ msq) {
  const int wg = (int)blockIdx.x;
  const int tid = (int)threadIdx.x;
  const int w = tid >> 6, lane = tid & 63;
  if (wg < 256) {
    size_t m0 = (size_t)wg * 256 + w * 32;
#pragma unroll 4
    for (int i = 0; i < 32; ++i) {
      size_t m = m0 + i;
      f32x4 f = *reinterpret_cast<const f32x4*>(memg + m * 256 + lane * 4);
      u32x2 p;
      p[0] = pk2(f[0], f[1]);
      p[1] = pk2(f[2], f[3]);
      *reinterpret_cast<u32x2*>(memA + m * 256 + lane * 4) = p;
      float sq = f[0] * f[0] + f[1] * f[1] + f[2] * f[2] + f[3] * f[3];
#pragma unroll
      for (int s2 = 32; s2; s2 >>= 1) sq += __shfl_xor(sq, s2);
      if (lane == 0) msq[m] = sq;
    }
  } else {
    size_t base = (size_t)(wg - 256) * 8192 + (size_t)tid * 16;
#pragma unroll
    for (int i = 0; i < 4; ++i) {
      f32x4 f = *reinterpret_cast<const f32x4*>(v + base + i * 4);
      u32x2 p;
      p[0] = pk2(f[0], f[1]);
      p[1] = pk2(f[2], f[3]);
      *reinterpret_cast<u32x2*>(vbf + base + i * 4) = p;
    }
  }
}

// ---------------- kernel 1: split-M flash ----------------
__global__ __launch_bounds__(512, 2) void k_stage1(
    const unsigned short* __restrict__ memA, const unsigned short* __restrict__ vbf,
    const float* __restrict__ msq, unsigned short* __restrict__ part_o,
    float* __restrict__ part_m, float* __restrict__ part_l) {
  __shared__ __align__(16) char lds[98304];  // Ab0 32K | Ab1 32K | Tb 32K
  char* const Ab0 = lds;
  char* const Ab1 = lds + 32768;
  char* const Tb = lds + 65536;

  const int tid = (int)threadIdx.x;
  const int w = tid >> 6;
  const int lane = tid & 63;
  const int g = lane >> 4;
  const int c = lane & 15;

  // XCD-chunked swizzle: 4 b-tiles of an m-split land on one XCD.
  const int bid = (int)blockIdx.x;
  const int swz = (bid & 7) * 32 + (bid >> 3);
  const int s = swz >> 2;        // m-split 0..63
  const int btile = swz & 3;     // b-tile 0..3
  const int mbase = s * 1024;
  const int bw = btile * 128 + w * 16;

  // ---- staging source (inverse-swizzled global addr; LDS dest linear) ----
  const char* memAc = (const char*)memA;
  const int mrow = w * 2 + (lane >> 5);  // row within 16-row instr group
  const int dbyte = ((lane & 31) * 16) ^ ((mrow & 7) << 4);
  const size_t a_src0 = ((size_t)mbase + (size_t)mrow) * 512 + (size_t)dbyte;

#define STAGE(bufp, t)                                                          \
  do {                                                                          \
    _Pragma("unroll") for (int i_ = 0; i_ < 4; ++i_) {                          \
      __builtin_amdgcn_global_load_lds(                                         \
          (const __attribute__((address_space(1))) void*)(memAc + a_src0 +      \
              (size_t)(t) * 32768 + (size_t)i_ * 8192),                         \
          (__attribute__((address_space(3))) void*)((bufp) + i_ * 8192 + w * 1024), \
          16, 0, 0);                                                            \
    }                                                                           \
  } while (0)

  // ---- per-wave persistent state ----
  f32x4 acc[16];
#pragma unroll
  for (int n = 0; n < 16; ++n) acc[n] = (f32x4)0.0f;
  float rm = -__builtin_inff(), rs = 0.f;

  // v B-fragments for this wave's 16 b-columns, held for all chunks
  s16x8 vreg[8];

  STAGE(Ab0, 0);
#pragma unroll
  for (int k = 0; k < 8; ++k)
    vreg[k] = *reinterpret_cast<const s16x8*>(vbf + (size_t)(bw + c) * 256 + k * 32 + g * 8);

  asm volatile("s_waitcnt vmcnt(0)" ::: "memory");
  __builtin_amdgcn_s_barrier();
  asm volatile("" ::: "memory");

  // transpose thread mapping
  const int db = tid & 31;    // d block (8 d each)
  const int mb = tid >> 5;    // m block (4 m each), 0..15
  const int d0 = db * 8, mm0 = mb * 4;

  for (int t = 0; t < NCHUNK; ++t) {
    char* Abc = (t & 1) ? Ab1 : Ab0;
    char* Abn = (t & 1) ? Ab0 : Ab1;
    if (t < NCHUNK - 1) STAGE(Abn, t + 1);

    // ---- transpose Ab[cur] -> Tb (vectorized: 4 b128 reads, 8 b64 writes) ----
    {
      u32x4 r0 = *reinterpret_cast<const u32x4*>(Abc + (((mm0 + 0) * 512 + d0 * 2) ^ (((mm0 + 0) & 7) << 4)));
      u32x4 r1 = *reinterpret_cast<const u32x4*>(Abc + (((mm0 + 1) * 512 + d0 * 2) ^ (((mm0 + 1) & 7) << 4)));
      u32x4 r2 = *reinterpret_cast<const u32x4*>(Abc + (((mm0 + 2) * 512 + d0 * 2) ^ (((mm0 + 2) & 7) << 4)));
      u32x4 r3 = *reinterpret_cast<const u32x4*>(Abc + (((mm0 + 3) * 512 + d0 * 2) ^ (((mm0 + 3) & 7) << 4)));
#pragma unroll
      for (int dd = 0; dd < 8; ++dd) {
        int sh = (dd & 1) * 16;
        unsigned h0 = (r0[dd >> 1] >> sh) & 0xffffu;
        unsigned h1 = (r1[dd >> 1] >> sh) & 0xffffu;
        unsigned h2 = (r2[dd >> 1] >> sh) & 0xffffu;
        unsigned h3 = (r3[dd >> 1] >> sh) & 0xffffu;
        u32x2 pw;
        pw[0] = h0 | (h1 << 16);
        pw[1] = h2 | (h3 << 16);
        int d = d0 + dd;
        *reinterpret_cast<u32x2*>(Tb + ((d * 128 + mm0 * 2) ^ TSWZ(d))) = pw;
      }
    }
    asm volatile("s_waitcnt lgkmcnt(0)" ::: "memory");
    __builtin_amdgcn_s_barrier();
    asm volatile("" ::: "memory");

    // ---- compute chunk ----
    const int mc = mbase + t * 64;
    // QK^T (swapped): S[m_frag][16 b cols]
    f32x4 S[4];
#pragma unroll
    for (int rf = 0; rf < 4; ++rf) S[rf] = (f32x4)0.0f;
#pragma unroll
    for (int k = 0; k < 8; ++k) {
#pragma unroll
      for (int rf = 0; rf < 4; ++rf) {
        s16x8 a = *reinterpret_cast<const s16x8*>(
            Abc + (((rf * 16 + c) * 512 + k * 64 + g * 16) ^ ((c & 7) << 4)));
        S[rf] = __builtin_amdgcn_mfma_f32_16x16x32_bf16(a, vreg[k], S[rf], 0, 0, 0);
      }
    }
    // bias: row m = rf*16 + 4g + r
#pragma unroll
    for (int rf = 0; rf < 4; ++rf) {
      f32x4 q = *reinterpret_cast<const f32x4*>(msq + mc + rf * 16 + g * 4);
#pragma unroll
      for (int r = 0; r < 4; ++r) S[rf][r] -= 0.5f * q[r];
    }
    // online softmax for this wave's 16 columns (col b = bw + c)
    float mx = -__builtin_inff();
#pragma unroll
    for (int rf = 0; rf < 4; ++rf)
#pragma unroll
      for (int r = 0; r < 4; ++r) mx = fmaxf(mx, S[rf][r]);
    mx = fmaxf(mx, __shfl_xor(mx, 16));
    mx = fmaxf(mx, __shfl_xor(mx, 32));
    float nm = fmaxf(rm, mx);
    float al = __expf(rm - nm);
    float ls = 0.f;
#pragma unroll
    for (int rf = 0; rf < 4; ++rf)
#pragma unroll
      for (int r = 0; r < 4; ++r) {
        float p = __expf(S[rf][r] - nm);
        S[rf][r] = p;
        ls += p;
      }
    ls += __shfl_xor(ls, 16);
    ls += __shfl_xor(ls, 32);
    rs = rs * al + ls;
    rm = nm;
    // rescale acc: acc rows are b = 4g + r; al lives at column-lane c = 4g+r
    f32x4 alv;
#pragma unroll
    for (int r = 0; r < 4; ++r) alv[r] = __shfl(al, 4 * g + r);
#pragma unroll
    for (int n = 0; n < 16; ++n) acc[n] *= alv;

    // PV: acc += P^T @ mem   (A = P^T via lane-group shuffle, B = Tb)
#pragma unroll
    for (int kk = 0; kk < 2; ++kk) {
      unsigned q00 = pk2(S[2 * kk][0], S[2 * kk][1]);
      unsigned q01 = pk2(S[2 * kk][2], S[2 * kk][3]);
      unsigned q10 = pk2(S[2 * kk + 1][0], S[2 * kk + 1][1]);
      unsigned q11 = pk2(S[2 * kk + 1][2], S[2 * kk + 1][3]);
      int srcA = ((lane & 16) >> 3) * 16 + c;
      int srcB = srcA + 16;
      unsigned a0 = (unsigned)__shfl((int)q00, srcA);
      unsigned b0 = (unsigned)__shfl((int)q10, srcA);
      unsigned a1 = (unsigned)__shfl((int)q01, srcA);
      unsigned b1 = (unsigned)__shfl((int)q11, srcA);
      unsigned a2 = (unsigned)__shfl((int)q00, srcB);
      unsigned b2 = (unsigned)__shfl((int)q10, srcB);
      unsigned a3 = (unsigned)__shfl((int)q01, srcB);
      unsigned b3 = (unsigned)__shfl((int)q11, srcB);
      bool hi = lane >= 32;
      u32x4 wv;
      wv[0] = hi ? b0 : a0;
      wv[1] = hi ? b1 : a1;
      wv[2] = hi ? b2 : a2;
      wv[3] = hi ? b3 : a3;
      s16x8 pa = __builtin_bit_cast(s16x8, wv);
#pragma unroll
      for (int n = 0; n < 16; ++n) {
        int d = n * 16 + c;
        s16x8 bm = *reinterpret_cast<const s16x8*>(Tb + ((d * 128 + kk * 64 + g * 16) ^ TSWZ(d)));
        acc[n] = __builtin_amdgcn_mfma_f32_16x16x32_bf16(pa, bm, acc[n], 0, 0, 0);
      }
    }

    asm volatile("s_waitcnt vmcnt(0) lgkmcnt(0)" ::: "memory");
    __builtin_amdgcn_s_barrier();
    asm volatile("" ::: "memory");
  }

  // ---- stats ----
  if (lane < 16) {
    int b = bw + lane;
    part_m[(size_t)b * NSPLIT + s] = rm;
    part_l[(size_t)b * NSPLIT + s] = rs;
  }

  // ---- epilogue: LDS-staged transposed store, contiguous part_o rows ----
  // wave tile: [bo(16)][d(256)] bf16, row stride 528 B
  {
    char* ep = lds;
    const int base_w = w * 8448;
#pragma unroll
    for (int n = 0; n < 16; ++n) {
#pragma unroll
      for (int r = 0; r < 4; ++r) {
        *reinterpret_cast<unsigned short*>(ep + base_w + (4 * g + r) * 528 + (n * 16 + c) * 2) =
            bf16rn(acc[n][r]);
      }
    }
    asm volatile("s_waitcnt lgkmcnt(0)" ::: "memory");
    __builtin_amdgcn_s_barrier();
    asm volatile("" ::: "memory");
#pragma unroll
    for (int j = 0; j < 8; ++j) {
      int u = j * 512 + tid;
      int wb = u >> 5;       // 0..127 (b offset within WG)
      int d8 = u & 31;       // 8-d group
      u32x4 val = *reinterpret_cast<const u32x4*>(ep + (wb >> 4) * 8448 + (wb & 15) * 528 + d8 * 16);
      *reinterpret_cast<u32x4*>(part_o +
          ((size_t)s * 512 + btile * 128 + wb) * 256 + d8 * 8) = val;
    }
  }
#undef STAGE
}

// ---------------- kernel 2: combine stats -> scale[b][s] ----------------
__global__ __launch_bounds__(64) void k_scale(const float* __restrict__ part_m,
                                              const float* __restrict__ part_l,
                                              float* __restrict__ scale) {
  int b = blockIdx.x, t = threadIdx.x;
  float m = part_m[(size_t)b * NSPLIT + t];
  float l = part_l[(size_t)b * NSPLIT + t];
  float M = m;
#pragma unroll
  for (int s2 = 32; s2; s2 >>= 1) M = fmaxf(M, __shfl_xor(M, s2));
  float e = __expf(m - M);
  float z = e * l;
#pragma unroll
  for (int s2 = 32; s2; s2 >>= 1) z += __shfl_xor(z, s2);
  scale[(size_t)b * NSPLIT + t] = e / z;
}

// ---------------- kernel 3: reduce partials + epilogue ----------------
__global__ __launch_bounds__(256) void k_out(const unsigned short* __restrict__ part_o,
                                             const float* __restrict__ scale,
                                             const float* __restrict__ v,
                                             const float* __restrict__ mask,
                                             float* __restrict__ out) {
  int b = blockIdx.x, d = threadIdx.x;
  __shared__ float sc[NSPLIT];
  if (d < NSPLIT) sc[d] = scale[(size_t)b * NSPLIT + d];
  __syncthreads();
  float a = 0.f;
  const unsigned short* po = part_o + (size_t)b * 256 + d;
#pragma unroll 8
  for (int gi = 0; gi < NSPLIT; ++gi)
    a = fmaf(sc[gi], bf2f(po[(size_t)gi * 131072]), a);
  size_t idx = (size_t)b * 256 + d;
  float vv = v[idx], mm = mask[idx];
  out[idx] = vv + 0.5f * (a - vv) * mm;
}

extern "C" void kernel_launch(void* const* d_in, const int* in_sizes, int n_in,
                              void* d_out, int out_size, void* d_ws, size_t ws_size,
                              hipStream_t stream) {
  const float* v = (const float*)d_in[0];       // [512,256]
  const float* mask = (const float*)d_in[1];    // [512,256]
  const float* memg = (const float*)d_in[2];    // [65536,256]
  float* out = (float*)d_out;

  char* ws = (char*)d_ws;
  const size_t SZ_PO = (size_t)NSPLIT * B_DIM * D_DIM * 2;   // 16 MiB
  const size_t SZ_MA = (size_t)M_TOT * D_DIM * 2;            // 32 MiB
  const size_t SZ_MS = (size_t)M_TOT * 4;                    // 256 KiB
  const size_t SZ_VB = (size_t)B_DIM * D_DIM * 2;            // 256 KiB
  const size_t SZ_ST = (size_t)B_DIM * NSPLIT * 4;           // 128 KiB
  unsigned short* part_o = (unsigned short*)ws;
  unsigned short* memA = (unsigned short*)(ws + SZ_PO);
  float* msq = (float*)(ws + SZ_PO + SZ_MA);
  unsigned short* vbf = (unsigned short*)(ws + SZ_PO + SZ_MA + SZ_MS);
  float* part_m = (float*)(ws + SZ_PO + SZ_MA + SZ_MS + SZ_VB);
  float* part_l = (float*)(ws + SZ_PO + SZ_MA + SZ_MS + SZ_VB + SZ_ST);
  float* scale = (float*)(ws + SZ_PO + SZ_MA + SZ_MS + SZ_VB + 2 * SZ_ST);

  k_prep<<<dim3(272), dim3(512), 0, stream>>>(memg, v, memA, vbf, msq);
  k_stage1<<<dim3(256), dim3(512), 0, stream>>>(memA, vbf, msq, part_o, part_m, part_l);
  k_scale<<<dim3(B_DIM), dim3(64), 0, stream>>>(part_m, part_l, scale);
  k_out<<<dim3(B_DIM), dim3(256), 0, stream>>>(part_o, scale, v, mask, out);
}